// Round 1
// baseline (312.413 us; speedup 1.0000x reference)
//
#include <hip/hip_runtime.h>
#include <stdint.h>
#include <stddef.h>

// MambaMesh random-walk + gather-recenter.
// CORRECTNESS-CRITICAL ASSUMPTION: JAX threefry_partitionable=True (default
// since jax 0.4.36):
//   split(key,n)[j]        = threefry2x32(key; 0, j)   (both output words)
//   random_bits(key,32,()) = fold-xor of threefry2x32(key; 0, 0)
// If absmax stays ~7, flip to the "original" (non-partitionable) layout:
//   split: counts = iota(2n), halves hashed pairwise, keys from concat reshape
//   bits : first output word of threefry2x32(key, [0]) with odd-size padding.

namespace {

__device__ __forceinline__ uint32_t rotl32(uint32_t x, int r) {
  return (x << r) | (x >> (32 - r));
}

// Threefry-2x32, 20 rounds — exactly JAX's threefry2x32_p.
__device__ __forceinline__ void tf2x32(uint32_t ka, uint32_t kb,
                                       uint32_t x0, uint32_t x1,
                                       uint32_t& o0, uint32_t& o1) {
  const uint32_t kc = ka ^ kb ^ 0x1BD11BDAu;
  x0 += ka; x1 += kb;
#define TF_R4(r0, r1, r2, r3)                          \
  x0 += x1; x1 = rotl32(x1, r0); x1 ^= x0;             \
  x0 += x1; x1 = rotl32(x1, r1); x1 ^= x0;             \
  x0 += x1; x1 = rotl32(x1, r2); x1 ^= x0;             \
  x0 += x1; x1 = rotl32(x1, r3); x1 ^= x0;
  TF_R4(13, 15, 26, 6)  x0 += kb; x1 += kc + 1u;
  TF_R4(17, 29, 16, 24) x0 += kc; x1 += ka + 2u;
  TF_R4(13, 15, 26, 6)  x0 += ka; x1 += kb + 3u;
  TF_R4(17, 29, 16, 24) x0 += kb; x1 += kc + 4u;
  TF_R4(13, 15, 26, 6)  x0 += kc; x1 += ka + 5u;
#undef TF_R4
  o0 = x0; o1 = x1;
}

// jax.random.randint(key, (), 0, span) for int32, partitionable threefry.
__device__ __forceinline__ uint32_t jax_randint(uint32_t ka, uint32_t kb,
                                                uint32_t span) {
  uint32_t s0a, s0b, s1a, s1b, h0, h1;
  tf2x32(ka, kb, 0u, 0u, s0a, s0b);  // _split(key)[0]
  tf2x32(ka, kb, 0u, 1u, s1a, s1b);  // _split(key)[1]
  tf2x32(s0a, s0b, 0u, 0u, h0, h1);
  const uint32_t hi = h0 ^ h1;       // random_bits(k1, 32, ())
  tf2x32(s1a, s1b, 0u, 0u, h0, h1);
  const uint32_t lo = h0 ^ h1;       // random_bits(k2, 32, ())
  uint32_t mult = 65536u % span;     // 2**(nbits/2) % span
  mult = (mult * mult) % span;
  uint32_t off = (hi % span) * mult + (lo % span);
  return off % span;
}

constexpr int WPB = 16;        // walks per block (4 per wave, 4 waves/block)
constexpr int BMSTRIDE = 641;  // bitmap words per walk: 20512 bits >= n_faces

__global__ __launch_bounds__(256) void walk_kernel(
    const float* __restrict__ xyz, const int* __restrict__ nbrs,
    const int* __restrict__ centers, const int* __restrict__ n_faces_p,
    const int* __restrict__ seq_len_p, float* __restrict__ out,
    int s0, int s2, int num_walks, int Lp1) {
  extern __shared__ uint32_t lds[];
  const int seq_stride = Lp1 + 1;  // +1: break LDS bank alignment
  uint32_t* bitmaps = lds;                      // [WPB][BMSTRIDE]
  int* seqs = (int*)(lds + WPB * BMSTRIDE);     // [WPB][seq_stride]

  const int tid = threadIdx.x;
  for (int j = tid; j < WPB * BMSTRIDE; j += blockDim.x) bitmaps[j] = 0u;
  __syncthreads();

  const int wave = tid >> 6, lane = tid & 63;
  const int wib = wave * 4 + lane;  // walk-in-block if lane < 4
  const int w = blockIdx.x * WPB + wib;
  if (lane >= 4 || w >= num_walks) return;

  const int N = *n_faces_p;   // 20000
  const int L = *seq_len_p;   // 63
  const int B = s0 / (3 * N);
  const int G = s2 / B;
  const int b = w / G;

  const int* __restrict__ nb = nbrs + (size_t)b * N * 3;
  uint32_t* vis = bitmaps + wib * BMSTRIDE;
  int* sq = seqs + wib * seq_stride;

  auto unvis = [&](int n) -> int {
    return ((vis[n >> 5] >> (n & 31)) & 1u) ? 0 : 1;
  };

  const int f0 = centers[w];

  // per-walk key: split(key(42), B*G)[w] = tf(0,42; 0, w)
  uint32_t ka, kb;
  tf2x32(0u, 42u, 0u, (uint32_t)w, ka, kb);

  sq[0] = f0;
  vis[f0 >> 5] |= 1u << (f0 & 31);

  int i = 1, bs = 1;
  while (i <= L) {
    // k, k1, k2, k3 = split(k, 4): subkey j = tf(k; 0, j)
    uint32_t nka, nkb;
    tf2x32(ka, kb, 0u, 0u, nka, nkb);  // new carry key

    const int cur = sq[i - 1];
    const int n0 = nb[cur * 3], n1 = nb[cur * 3 + 1], n2 = nb[cur * 3 + 2];
    const int u0 = unvis(n0), u1 = unvis(n1), u2 = unvis(n2);
    const int cnt = u0 + u1 + u2;

    int to_add;
    bool hit = false;
    int bsf = bs;
    if (cnt > 0) {
      // cand = _pick(k1, nb, unv, cnt)
      uint32_t k1a, k1b;
      tf2x32(ka, kb, 0u, 1u, k1a, k1b);
      const int target = (int)jax_randint(k1a, k1b, (uint32_t)cnt) + 1;
      const int cs0 = u0, cs1 = u0 + u1;  // cs2 == cnt
      to_add = (cs0 == target) ? n0
             : (cs1 == target) ? n1
             : (cnt == target) ? n2 : n0;
    } else {
      // backtrack while-loop, seeded with k2 = tf(k; 0, 2)
      uint32_t kka, kkb;
      tf2x32(ka, kb, 0u, 2u, kka, kkb);
      bool found = false;
      int ta = 0, bsc = bs;
      while (!found && i > bsc) {
        uint32_t ca, cb, kpa, kpb;
        tf2x32(kka, kkb, 0u, 0u, ca, cb);   // kk = split(kk)[0]
        tf2x32(kka, kkb, 0u, 1u, kpa, kpb); // kp = split(kk)[1]
        const int back = sq[i - bsc - 1];
        const int m0 = nb[back * 3], m1 = nb[back * 3 + 1], m2 = nb[back * 3 + 2];
        const int v0 = unvis(m0), v1 = unvis(m1), v2 = unvis(m2);
        const int bc = v0 + v1 + v2;
        if (bc > 0) {
          const int target = (int)jax_randint(kpa, kpb, (uint32_t)bc) + 1;
          const int cs0 = v0, cs1 = v0 + v1;
          ta = (cs0 == target) ? m0
             : (cs1 == target) ? m1
             : (bc == target) ? m2 : m0;
          found = true;  // bs_c stays
        } else {
          bsc += 2;
        }
        kka = ca; kkb = cb;
      }
      if (found) {
        to_add = ta; hit = true; bsf = bsc;
      } else {
        uint32_t k3a, k3b;
        tf2x32(ka, kb, 0u, 3u, k3a, k3b);
        to_add = (int)jax_randint(k3a, k3b, (uint32_t)N);
      }
    }

    int i_new;
    if (hit) {
      i_new = i - bsf;
      for (int a = i_new; a < i; ++a) sq[a] = to_add;  // ref's seq-splat
      bs = bsf;
    } else {
      i_new = i;
      bs = 1;
    }
    vis[to_add >> 5] |= 1u << (to_add & 31);
    sq[i_new] = to_add;
    i = i_new + 1;
    ka = nka; kb = nkb;
  }

  // epilogue: out[w, t, :] = xyz[b, sq[t], :] - xyz[b, f0, :]
  const float* __restrict__ xb = xyz + (size_t)b * N * 3;
  const float cx = xb[(size_t)f0 * 3 + 0];
  const float cy = xb[(size_t)f0 * 3 + 1];
  const float cz = xb[(size_t)f0 * 3 + 2];
  float* __restrict__ ob = out + (size_t)w * Lp1 * 3;
  for (int t = 0; t < Lp1; ++t) {
    const int node = sq[t];
    ob[t * 3 + 0] = xb[(size_t)node * 3 + 0] - cx;
    ob[t * 3 + 1] = xb[(size_t)node * 3 + 1] - cy;
    ob[t * 3 + 2] = xb[(size_t)node * 3 + 2] - cz;
  }
}

}  // namespace

extern "C" void kernel_launch(void* const* d_in, const int* in_sizes, int n_in,
                              void* d_out, int out_size, void* d_ws, size_t ws_size,
                              hipStream_t stream) {
  const float* xyz      = (const float*)d_in[0];
  const int*   nbrs     = (const int*)d_in[1];
  const int*   centers  = (const int*)d_in[2];
  const int*   n_faces  = (const int*)d_in[3];
  const int*   seq_len  = (const int*)d_in[4];
  float* out = (float*)d_out;

  const int s0 = in_sizes[0];            // B*N*3
  const int s2 = in_sizes[2];            // B*G
  const int num_walks = s2;              // 4096
  const int Lp1 = out_size / (3 * num_walks);  // seq_len+1 = 64

  const int blocks = (num_walks + WPB - 1) / WPB;  // 256
  const size_t lds_bytes =
      (size_t)WPB * (size_t)(BMSTRIDE + Lp1 + 1) * sizeof(uint32_t);  // ~45 KB

  walk_kernel<<<blocks, 256, lds_bytes, stream>>>(
      xyz, nbrs, centers, n_faces, seq_len, out, s0, s2, num_walks, Lp1);
}

// Round 2
// 134.533 us; speedup vs baseline: 2.3222x; 2.3222x over previous
//
#include <hip/hip_runtime.h>
#include <stdint.h>
#include <stddef.h>

// MambaMesh random-walk + gather-recenter.  R2: walk-per-wave restructure.
// PRNG (verified bit-exact in R1, absmax 0.0): JAX partitionable Threefry —
//   split(key,n)[j]        = threefry2x32(key; 0, j)   (both output words)
//   random_bits(key,32,()) = xor-fold of threefry2x32(key; 0, 0)
// Key insight: per-step randint bits depend only on the carry-key chain
// k_{c+1} = tf(k_c;0,0), NOT on walk state (state only selects span 1/2/3/N).
// So: Phase A hoists all hashing (chain redundant across lanes, per-step
// 5-hash trees one-per-lane); Phase B is a cheap wave-uniform decision loop.

namespace {

__device__ __forceinline__ uint32_t rotl32(uint32_t x, int r) {
  return (x << r) | (x >> (32 - r));
}

// Threefry-2x32, 20 rounds — exactly JAX's threefry2x32_p.
__device__ __forceinline__ void tf2x32(uint32_t ka, uint32_t kb,
                                       uint32_t x0, uint32_t x1,
                                       uint32_t& o0, uint32_t& o1) {
  const uint32_t kc = ka ^ kb ^ 0x1BD11BDAu;
  x0 += ka; x1 += kb;
#define TF_R4(r0, r1, r2, r3)                          \
  x0 += x1; x1 = rotl32(x1, r0); x1 ^= x0;             \
  x0 += x1; x1 = rotl32(x1, r1); x1 ^= x0;             \
  x0 += x1; x1 = rotl32(x1, r2); x1 ^= x0;             \
  x0 += x1; x1 = rotl32(x1, r3); x1 ^= x0;
  TF_R4(13, 15, 26, 6)  x0 += kb; x1 += kc + 1u;
  TF_R4(17, 29, 16, 24) x0 += kc; x1 += ka + 2u;
  TF_R4(13, 15, 26, 6)  x0 += ka; x1 += kb + 3u;
  TF_R4(17, 29, 16, 24) x0 += kb; x1 += kc + 4u;
  TF_R4(13, 15, 26, 6)  x0 += kc; x1 += ka + 5u;
#undef TF_R4
  o0 = x0; o1 = x1;
}

// (hi, lo) bits of jax.random.randint(key, (), 0, span): span-independent.
__device__ __forceinline__ void randbits(uint32_t ka, uint32_t kb,
                                         uint32_t& hi, uint32_t& lo) {
  uint32_t s0a, s0b, s1a, s1b, h0, h1;
  tf2x32(ka, kb, 0u, 0u, s0a, s0b);   // split(key)[0]
  tf2x32(ka, kb, 0u, 1u, s1a, s1b);   // split(key)[1]
  tf2x32(s0a, s0b, 0u, 0u, h0, h1);
  hi = h0 ^ h1;
  tf2x32(s1a, s1b, 0u, 0u, h0, h1);
  lo = h0 ^ h1;
}

// randint result for span in {1,2,3} — closed forms, no runtime division.
__device__ __forceinline__ uint32_t r_small(uint32_t hi, uint32_t lo, int span) {
  // span==3: mult = (65536%3)^2 % 3 = 1 -> r = (hi%3 + lo%3) % 3
  // span==2: mult = 0                  -> r = lo & 1
  // span==1: r = 0
  return span == 3 ? (hi % 3u + lo % 3u) % 3u
       : (span == 2 ? (lo & 1u) : 0u);
}

__device__ __forceinline__ uint32_t r_generic(uint32_t hi, uint32_t lo,
                                              uint32_t span) {
  uint32_t mult = 65536u % span;
  mult = (mult * mult) % span;
  return ((hi % span) * mult + (lo % span)) % span;
}

constexpr int WAVES = 4;   // walks per block (one per wave)
constexpr int BMW = 640;   // visited bitmap words per walk (20480 bits)

__global__ __launch_bounds__(256) void walk_kernel(
    const float* __restrict__ xyz, const int* __restrict__ nbrs,
    const int* __restrict__ centers, const int* __restrict__ n_faces_p,
    const int* __restrict__ seq_len_p, float* __restrict__ out,
    int s0, int s2, int num_walks, int Lp1) {
  __shared__ uint32_t vis[WAVES][BMW];   // 10240 B
  __shared__ uint4 keys[WAVES][64];      // (ka, kb, hi, lo) per step; 4096 B
  __shared__ int seq[WAVES][80];         // 1280 B

  const int tid = threadIdx.x;
  const int wv = tid >> 6, lane = tid & 63;
  const int w = blockIdx.x * WAVES + wv;
  const bool active = (w < num_walks);

  // ---- Phase A: all hashing, parallel across lanes -----------------------
  if (active) {
    for (int j = lane; j < BMW; j += 64) vis[wv][j] = 0u;

    uint32_t ka, kb;
    tf2x32(0u, 42u, 0u, (uint32_t)w, ka, kb);  // k_0 = split(key(42),BG)[w]
    uint32_t ska = ka, skb = kb;               // lane 0 keeps k_0
#pragma clang loop unroll(disable)
    for (int c = 1; c < 64; ++c) {             // carry chain (serial, redundant)
      tf2x32(ka, kb, 0u, 0u, ka, kb);          // k_c
      if (lane == c) { ska = ka; skb = kb; }   // lane c keeps k_c
    }
    // per-lane randint tree for step `lane`: k1 = tf(k_c;0,1) -> (hi,lo)
    uint32_t k1a, k1b, hi, lo;
    tf2x32(ska, skb, 0u, 1u, k1a, k1b);
    randbits(k1a, k1b, hi, lo);
    keys[wv][lane] = make_uint4(ska, skb, hi, lo);
  }
  __syncthreads();
  if (!active) return;

  // ---- Phase B: wave-uniform decision loop -------------------------------
  const int N = *n_faces_p;    // 20000
  const int L = *seq_len_p;    // 63
  const int B = s0 / (3 * N);
  const int G = num_walks / B;
  const int b = w / G;

  const int* __restrict__ nb = nbrs + (size_t)b * N * 3;
  const int f0 = centers[w];
  vis[wv][f0 >> 5] |= 1u << (f0 & 31);
  seq[wv][0] = f0;

  auto unvis = [&](int n) -> int {
    return 1 - (int)((vis[wv][n >> 5] >> (n & 31)) & 1u);
  };

  int cur = f0;
  const int* nbp = nb + (size_t)cur * 3;
  int rn0 = nbp[0], rn1 = nbp[1], rn2 = nbp[2];  // in-flight neighbor row

  int i = 1, bs = 1, c = 0;
  uint32_t extka = 0, extkb = 0;
  int extc = -1;  // lazy chain extension state (only after backtracks)

  while (i <= L) {
    const int idx = c; ++c;
    uint32_t kia, kib, hi, lo;
    if (idx < 64) {
      const uint4 q = keys[wv][idx];
      kia = q.x; kib = q.y; hi = q.z; lo = q.w;
    } else {  // rare: >63 iterations after backtracking
      if (extc < 0) { const uint4 q = keys[wv][63]; extka = q.x; extkb = q.y; extc = 63; }
      while (extc < idx) { tf2x32(extka, extkb, 0u, 0u, extka, extkb); ++extc; }
      kia = extka; kib = extkb;
      uint32_t k1a, k1b;
      tf2x32(kia, kib, 0u, 1u, k1a, k1b);
      randbits(k1a, k1b, hi, lo);
    }

    const int n0 = rn0, n1 = rn1, n2 = rn2;
    const int u0 = unvis(n0), u1 = unvis(n1), u2 = unvis(n2);
    const int cnt = u0 + u1 + u2;

    int to_add;
    bool hit = false;
    int bsf = bs;
    if (cnt > 0) {
      const int target = (int)r_small(hi, lo, cnt) + 1;
      to_add = (u0 == target) ? n0 : ((u0 + u1 == target) ? n1 : n2);
    } else {
      // ---- rare backtrack path (live hashing, bit-exact) ----
      uint32_t kka, kkb;
      tf2x32(kia, kib, 0u, 2u, kka, kkb);  // k2
      bool found = false;
      int ta = 0, bsc = bs;
      while (!found && i > bsc) {
        uint32_t ca, cb, kpa, kpb;
        tf2x32(kka, kkb, 0u, 0u, ca, cb);    // kk = split[0]
        tf2x32(kka, kkb, 0u, 1u, kpa, kpb);  // kp = split[1]
        const int back = seq[wv][i - bsc - 1];
        const int* bp = nb + (size_t)back * 3;
        const int m0 = bp[0], m1 = bp[1], m2 = bp[2];
        const int v0 = unvis(m0), v1 = unvis(m1), v2 = unvis(m2);
        const int bc = v0 + v1 + v2;
        if (bc > 0) {
          uint32_t bhi, blo;
          randbits(kpa, kpb, bhi, blo);
          const int t2 = (int)r_small(bhi, blo, bc) + 1;
          ta = (v0 == t2) ? m0 : ((v0 + v1 == t2) ? m1 : m2);
          found = true;
        } else {
          bsc += 2;
        }
        kka = ca; kkb = cb;
      }
      if (found) {
        to_add = ta; hit = true; bsf = bsc;
      } else {
        uint32_t k3a, k3b, rhi, rlo;
        tf2x32(kia, kib, 0u, 3u, k3a, k3b);  // k3
        randbits(k3a, k3b, rhi, rlo);
        to_add = (int)r_generic(rhi, rlo, (uint32_t)N);
      }
    }

    int i_new;
    if (hit) {
      i_new = i - bsf;
      for (int a = i_new; a < i; ++a) seq[wv][a] = to_add;  // ref's seq-splat
      bs = bsf;
    } else {
      i_new = i;
      bs = 1;
    }
    vis[wv][to_add >> 5] |= 1u << (to_add & 31);
    seq[wv][i_new] = to_add;
    i = i_new + 1;
    cur = to_add;
    const int* np = nb + (size_t)cur * 3;   // prefetch next row
    rn0 = np[0]; rn1 = np[1]; rn2 = np[2];
  }

  // ---- Epilogue: lane t gathers position t ------------------------------
  const float* __restrict__ xb = xyz + (size_t)b * N * 3;
  const float cx = xb[(size_t)f0 * 3 + 0];
  const float cy = xb[(size_t)f0 * 3 + 1];
  const float cz = xb[(size_t)f0 * 3 + 2];
  float* __restrict__ ob = out + (size_t)w * Lp1 * 3;
  for (int t = lane; t < Lp1; t += 64) {
    const int node = seq[wv][t];
    ob[t * 3 + 0] = xb[(size_t)node * 3 + 0] - cx;
    ob[t * 3 + 1] = xb[(size_t)node * 3 + 1] - cy;
    ob[t * 3 + 2] = xb[(size_t)node * 3 + 2] - cz;
  }
}

}  // namespace

extern "C" void kernel_launch(void* const* d_in, const int* in_sizes, int n_in,
                              void* d_out, int out_size, void* d_ws, size_t ws_size,
                              hipStream_t stream) {
  const float* xyz     = (const float*)d_in[0];
  const int*   nbrs    = (const int*)d_in[1];
  const int*   centers = (const int*)d_in[2];
  const int*   n_faces = (const int*)d_in[3];
  const int*   seq_len = (const int*)d_in[4];
  float* out = (float*)d_out;

  const int s0 = in_sizes[0];                  // B*N*3
  const int s2 = in_sizes[2];                  // B*G
  const int num_walks = s2;                    // 4096
  const int Lp1 = out_size / (3 * num_walks);  // 64

  const int blocks = (num_walks + WAVES - 1) / WAVES;  // 1024
  walk_kernel<<<blocks, 256, 0, stream>>>(
      xyz, nbrs, centers, n_faces, seq_len, out, s0, s2, num_walks, Lp1);
}

// Round 3
// 108.319 us; speedup vs baseline: 2.8842x; 1.2420x over previous
//
#include <hip/hip_runtime.h>
#include <stdint.h>
#include <stddef.h>

// MambaMesh random-walk + gather-recenter.  R3: dedup the carry-key chain.
// PRNG (bit-exact vs JAX partitionable Threefry, verified R1/R2, absmax 0.0):
//   split(key,n)[j]        = threefry2x32(key; 0, j)   (both output words)
//   random_bits(key,32,()) = xor-fold of threefry2x32(key; 0, 0)
// R2 lesson (rocprof): 63% VALUBusy, ~2/3 of it the per-wave-redundant chain
// (walk-per-wave layout pays 64 serial hashes as wave-instrs per walk).
// R3: block = 1024 thr = 16 waves = 16 walks.
//   A0: wave 0 lanes 0..15 compute the 16 chains walk-per-lane  (~6 us, serial floor)
//   A1: lane c computes step-c randint tree; precomputes span-{2,3} pick codes
//   B : wave-uniform decide loop; visited via in-register wave membership
//       (lane j = j-th visited node, 3 v_cmp + __any), seq in registers.

namespace {

__device__ __forceinline__ uint32_t rotl32(uint32_t x, int r) {
  return (x << r) | (x >> (32 - r));
}

// Threefry-2x32, 20 rounds — exactly JAX's threefry2x32_p.
__device__ __forceinline__ void tf2x32(uint32_t ka, uint32_t kb,
                                       uint32_t x0, uint32_t x1,
                                       uint32_t& o0, uint32_t& o1) {
  const uint32_t kc = ka ^ kb ^ 0x1BD11BDAu;
  x0 += ka; x1 += kb;
#define TF_R4(r0, r1, r2, r3)                          \
  x0 += x1; x1 = rotl32(x1, r0); x1 ^= x0;             \
  x0 += x1; x1 = rotl32(x1, r1); x1 ^= x0;             \
  x0 += x1; x1 = rotl32(x1, r2); x1 ^= x0;             \
  x0 += x1; x1 = rotl32(x1, r3); x1 ^= x0;
  TF_R4(13, 15, 26, 6)  x0 += kb; x1 += kc + 1u;
  TF_R4(17, 29, 16, 24) x0 += kc; x1 += ka + 2u;
  TF_R4(13, 15, 26, 6)  x0 += ka; x1 += kb + 3u;
  TF_R4(17, 29, 16, 24) x0 += kb; x1 += kc + 4u;
  TF_R4(13, 15, 26, 6)  x0 += kc; x1 += ka + 5u;
#undef TF_R4
  o0 = x0; o1 = x1;
}

// (hi, lo) bits of jax.random.randint(key, (), 0, span): span-independent.
__device__ __forceinline__ void randbits(uint32_t ka, uint32_t kb,
                                         uint32_t& hi, uint32_t& lo) {
  uint32_t s0a, s0b, s1a, s1b, h0, h1;
  tf2x32(ka, kb, 0u, 0u, s0a, s0b);   // split(key)[0]
  tf2x32(ka, kb, 0u, 1u, s1a, s1b);   // split(key)[1]
  tf2x32(s0a, s0b, 0u, 0u, h0, h1);
  hi = h0 ^ h1;
  tf2x32(s1a, s1b, 0u, 0u, h0, h1);
  lo = h0 ^ h1;
}

__device__ __forceinline__ uint32_t r_generic(uint32_t hi, uint32_t lo,
                                              uint32_t span) {
  uint32_t mult = 65536u % span;
  mult = (mult * mult) % span;
  return ((hi % span) * mult + (lo % span)) % span;
}

// pick code: r3 (span=3 result) in bits 0..1, r2 (span=2 result) in bit 2.
__device__ __forceinline__ uint32_t pick_code(uint32_t hi, uint32_t lo) {
  return ((hi % 3u + lo % 3u) % 3u) | ((lo & 1u) << 2);
}

constexpr int WPB = 16;  // walks per block, one per wave (block = 1024 thr)
constexpr int CH = 64;   // cached chain length (covers seq_len 63)

__global__ __launch_bounds__(1024) void walk_kernel(
    const float* __restrict__ xyz, const int* __restrict__ nbrs,
    const int* __restrict__ centers, const int* __restrict__ n_faces_p,
    const int* __restrict__ seq_len_p, float* __restrict__ out,
    int s0, int num_walks, int Lp1) {
  __shared__ uint2 keys[WPB][CH + 1];   // [walk][step] carry keys; +1 pad (8.3 KB)
  __shared__ uint32_t pre[WPB][CH];     // packed pick codes (4 KB)

  const int tid = threadIdx.x;
  const int wv = tid >> 6, lane = tid & 63;
  const int w0 = blockIdx.x * WPB;
  const int w = w0 + wv;

  // ---- Phase A0: wave 0 computes the block's 16 carry-key chains ---------
  if (wv == 0 && lane < WPB && (w0 + lane) < num_walks) {
    uint32_t ka, kb;
    tf2x32(0u, 42u, 0u, (uint32_t)(w0 + lane), ka, kb);  // k_0 for walk
    keys[lane][0] = make_uint2(ka, kb);
#pragma clang loop unroll(disable)
    for (int c = 1; c < CH; ++c) {
      tf2x32(ka, kb, 0u, 0u, ka, kb);
      keys[lane][c] = make_uint2(ka, kb);
    }
  }
  __syncthreads();

  // ---- Phase A1: lane c = step-c randint tree for this wave's walk -------
  if (w < num_walks) {
    const uint2 kc = keys[wv][lane];
    uint32_t k1a, k1b, hi, lo;
    tf2x32(kc.x, kc.y, 0u, 1u, k1a, k1b);  // k1 = split(k,4)[1]
    randbits(k1a, k1b, hi, lo);
    pre[wv][lane] = pick_code(hi, lo);
  }
  __syncthreads();
  if (w >= num_walks) return;

  // ---- Phase B: wave-uniform decision loop -------------------------------
  const int N = *n_faces_p;    // 20000
  const int L = *seq_len_p;    // 63
  const int B = s0 / (3 * N);
  const int G = num_walks / B;
  const int b = w / G;

  const int* __restrict__ nb = nbrs + (size_t)b * N * 3;
  const int f0 = centers[w];

  // visited set: lane j holds the j-th visited node (slot 0 = f0).
  int hist  = (lane == 0) ? f0 : -1;
  int hist2 = -1;              // slots 64..127 (backtrack overflow; ~never)
  // seq in registers: lane t holds seq[t].
  int seqr = (lane == 0) ? f0 : -1;

  uint32_t extka = 0, extkb = 0;
  int extc = -1;  // lazy chain extension beyond CH (only after backtracks)

  auto get_key = [&](int idx, uint32_t& ra, uint32_t& rb) {
    if (idx < CH) {
      const uint2 q = keys[wv][idx]; ra = q.x; rb = q.y;
    } else {
      if (extc < 0) { const uint2 q = keys[wv][CH - 1]; extka = q.x; extkb = q.y; extc = CH - 1; }
      while (extc < idx) { tf2x32(extka, extkb, 0u, 0u, extka, extkb); ++extc; }
      ra = extka; rb = extkb;
    }
  };

  int3 row = *reinterpret_cast<const int3*>(nb + 3 * (size_t)f0);
  int i = 1, bs = 1, c = 0;

  while (i <= L) {
    const int idx = c; ++c;
    const bool deep = (idx >= CH);  // hist2 in use (slots filled = idx+1)

    const int n0 = row.x, n1 = row.y, n2 = row.z;
    int v0 = __any(hist == n0), v1 = __any(hist == n1), v2 = __any(hist == n2);
    if (deep) {
      v0 |= __any(hist2 == n0); v1 |= __any(hist2 == n1); v2 |= __any(hist2 == n2);
    }
    const int u0 = 1 - v0, u1 = 1 - v1, u2 = 1 - v2;
    const int cnt = u0 + u1 + u2;

    int to_add;
    bool hit = false;
    int bsf = bs;
    if (cnt > 0) {
      uint32_t code;
      if (idx < CH) {
        code = pre[wv][idx];
      } else {  // rare: live tree beyond cached steps
        uint32_t ia, ib, k1a, k1b, hi, lo;
        get_key(idx, ia, ib);
        tf2x32(ia, ib, 0u, 1u, k1a, k1b);
        randbits(k1a, k1b, hi, lo);
        code = pick_code(hi, lo);
      }
      const int r3 = (int)(code & 3u), r2 = (int)((code >> 2) & 1u);
      const int target = (cnt == 3 ? r3 : (cnt == 2 ? r2 : 0)) + 1;
      to_add = (u0 == target) ? n0 : ((u0 + u1 == target) ? n1 : n2);
    } else {
      // ---- rare backtrack path (live hashing, bit-exact) ----
      uint32_t kia, kib;
      get_key(idx, kia, kib);
      uint32_t kka, kkb;
      tf2x32(kia, kib, 0u, 2u, kka, kkb);  // k2
      bool found = false;
      int ta = 0, bsc = bs;
      while (!found && i > bsc) {
        uint32_t ca, cb, kpa, kpb;
        tf2x32(kka, kkb, 0u, 0u, ca, cb);    // kk = split[0]
        tf2x32(kka, kkb, 0u, 1u, kpa, kpb);  // kp = split[1]
        const int back = __shfl(seqr, i - bsc - 1);
        const int3 br = *reinterpret_cast<const int3*>(nb + 3 * (size_t)back);
        int w0m = __any(hist == br.x), w1m = __any(hist == br.y), w2m = __any(hist == br.z);
        if (deep) {
          w0m |= __any(hist2 == br.x); w1m |= __any(hist2 == br.y); w2m |= __any(hist2 == br.z);
        }
        const int e0 = 1 - w0m, e1 = 1 - w1m, e2 = 1 - w2m;
        const int bc = e0 + e1 + e2;
        if (bc > 0) {
          uint32_t bhi, blo;
          randbits(kpa, kpb, bhi, blo);
          const uint32_t bcode = pick_code(bhi, blo);
          const int r3 = (int)(bcode & 3u), r2 = (int)((bcode >> 2) & 1u);
          const int t2 = (bc == 3 ? r3 : (bc == 2 ? r2 : 0)) + 1;
          ta = (e0 == t2) ? br.x : ((e0 + e1 == t2) ? br.y : br.z);
          found = true;
        } else {
          bsc += 2;
        }
        kka = ca; kkb = cb;
      }
      if (found) {
        to_add = ta; hit = true; bsf = bsc;
      } else {
        uint32_t k3a, k3b, rhi, rlo;
        tf2x32(kia, kib, 0u, 3u, k3a, k3b);  // k3
        randbits(k3a, k3b, rhi, rlo);
        to_add = (int)r_generic(rhi, rlo, (uint32_t)N);
      }
    }

    int i_new, up;
    if (hit) { i_new = i - bsf; bs = bsf; up = i - 1; }   // splat [i_new, i)
    else     { i_new = i;       bs = 1;   up = i; }
    seqr = (lane >= i_new && lane <= up) ? to_add : seqr;

    const int slot = idx + 1;
    if (slot < CH)            hist  = (lane == slot)      ? to_add : hist;
    else if (slot < 2 * CH)   hist2 = (lane == slot - CH) ? to_add : hist2;
    // slot >= 128: needs ~32 backtracks in one walk — P < 1e-100 for this data.

    i = i_new + 1;
    row = *reinterpret_cast<const int3*>(nb + 3 * (size_t)to_add);  // prefetch
  }

  // ---- Epilogue: lane t holds seq[t] in-register -------------------------
  const float* __restrict__ xb = xyz + (size_t)b * N * 3;
  const float cx = xb[3 * (size_t)f0 + 0];
  const float cy = xb[3 * (size_t)f0 + 1];
  const float cz = xb[3 * (size_t)f0 + 2];
  if (lane < Lp1) {
    const int node = seqr;
    float3 v;
    v.x = xb[3 * (size_t)node + 0] - cx;
    v.y = xb[3 * (size_t)node + 1] - cy;
    v.z = xb[3 * (size_t)node + 2] - cz;
    *reinterpret_cast<float3*>(out + ((size_t)w * Lp1 + lane) * 3) = v;
  }
}

}  // namespace

extern "C" void kernel_launch(void* const* d_in, const int* in_sizes, int n_in,
                              void* d_out, int out_size, void* d_ws, size_t ws_size,
                              hipStream_t stream) {
  const float* xyz     = (const float*)d_in[0];
  const int*   nbrs    = (const int*)d_in[1];
  const int*   centers = (const int*)d_in[2];
  const int*   n_faces = (const int*)d_in[3];
  const int*   seq_len = (const int*)d_in[4];
  float* out = (float*)d_out;

  const int s0 = in_sizes[0];                  // B*N*3
  const int num_walks = in_sizes[2];           // B*G = 4096
  const int Lp1 = out_size / (3 * num_walks);  // 64

  const int blocks = (num_walks + WPB - 1) / WPB;  // 256
  walk_kernel<<<blocks, WPB * 64, 0, stream>>>(
      xyz, nbrs, centers, n_faces, seq_len, out, s0, num_walks, Lp1);
}

// Round 4
// 106.842 us; speedup vs baseline: 2.9241x; 1.0138x over previous
//
#include <hip/hip_runtime.h>
#include <stdint.h>
#include <stddef.h>

// MambaMesh random-walk + gather-recenter.  R4: kill the load-latency chain.
// PRNG (bit-exact vs JAX partitionable Threefry, verified R1-R3, absmax 0.0):
//   split(key,n)[j]        = threefry2x32(key; 0, j)   (both output words)
//   random_bits(key,32,()) = xor-fold of threefry2x32(key; 0, 0)
// R3 lesson (rocprof): VALUBusy 26% — latency-bound. Phase-B row loads are
// serial HBM misses (~900 cyc x 63); A0's serial chain idles 15/16 waves.
// R4: (1) waves 1-15 prewarm nb+xyz into L2 during A0 (HBM 900 -> L2 ~220);
//     (2) speculative triplet prefetch: issue nb[n0],nb[n1],nb[n2] on row
//         arrival — next row is a select, decisions off the load path;
//     (3) first row in flight from kernel top; pre-codes LDS-prefetched.

namespace {

__device__ __forceinline__ uint32_t rotl32(uint32_t x, int r) {
  return (x << r) | (x >> (32 - r));
}

// Threefry-2x32, 20 rounds — exactly JAX's threefry2x32_p.
__device__ __forceinline__ void tf2x32(uint32_t ka, uint32_t kb,
                                       uint32_t x0, uint32_t x1,
                                       uint32_t& o0, uint32_t& o1) {
  const uint32_t kc = ka ^ kb ^ 0x1BD11BDAu;
  x0 += ka; x1 += kb;
#define TF_R4(r0, r1, r2, r3)                          \
  x0 += x1; x1 = rotl32(x1, r0); x1 ^= x0;             \
  x0 += x1; x1 = rotl32(x1, r1); x1 ^= x0;             \
  x0 += x1; x1 = rotl32(x1, r2); x1 ^= x0;             \
  x0 += x1; x1 = rotl32(x1, r3); x1 ^= x0;
  TF_R4(13, 15, 26, 6)  x0 += kb; x1 += kc + 1u;
  TF_R4(17, 29, 16, 24) x0 += kc; x1 += ka + 2u;
  TF_R4(13, 15, 26, 6)  x0 += ka; x1 += kb + 3u;
  TF_R4(17, 29, 16, 24) x0 += kb; x1 += kc + 4u;
  TF_R4(13, 15, 26, 6)  x0 += kc; x1 += ka + 5u;
#undef TF_R4
  o0 = x0; o1 = x1;
}

// (hi, lo) bits of jax.random.randint(key, (), 0, span): span-independent.
__device__ __forceinline__ void randbits(uint32_t ka, uint32_t kb,
                                         uint32_t& hi, uint32_t& lo) {
  uint32_t s0a, s0b, s1a, s1b, h0, h1;
  tf2x32(ka, kb, 0u, 0u, s0a, s0b);   // split(key)[0]
  tf2x32(ka, kb, 0u, 1u, s1a, s1b);   // split(key)[1]
  tf2x32(s0a, s0b, 0u, 0u, h0, h1);
  hi = h0 ^ h1;
  tf2x32(s1a, s1b, 0u, 0u, h0, h1);
  lo = h0 ^ h1;
}

__device__ __forceinline__ uint32_t r_generic(uint32_t hi, uint32_t lo,
                                              uint32_t span) {
  uint32_t mult = 65536u % span;
  mult = (mult * mult) % span;
  return ((hi % span) * mult + (lo % span)) % span;
}

// pick code: r3 (span=3 result) in bits 0..1, r2 (span=2 result) in bit 2.
__device__ __forceinline__ uint32_t pick_code(uint32_t hi, uint32_t lo) {
  return ((hi % 3u + lo % 3u) % 3u) | ((lo & 1u) << 2);
}

constexpr int WPB = 16;  // walks per block, one per wave (block = 1024 thr)
constexpr int CH = 64;   // cached chain length (covers seq_len 63)

__global__ __launch_bounds__(1024) void walk_kernel(
    const float* __restrict__ xyz, const int* __restrict__ nbrs,
    const int* __restrict__ centers, const int* __restrict__ n_faces_p,
    const int* __restrict__ seq_len_p, float* __restrict__ out,
    int s0, int num_walks, int Lp1) {
  __shared__ uint2 keys[WPB][CH + 1];   // [walk][step] carry keys (+1 pad)
  __shared__ uint32_t pre[WPB][CH];     // packed pick codes

  const int tid = threadIdx.x;
  const int wv = tid >> 6, lane = tid & 63;
  const int w0 = blockIdx.x * WPB;
  const int w = w0 + wv;
  const bool active = (w < num_walks);

  const int N = *n_faces_p;    // 20000
  const int L = *seq_len_p;    // 63
  const int B = s0 / (3 * N);
  const int G = num_walks / B;
  const int b = (active ? w : w0) / G;
  const int* __restrict__ nb  = nbrs + (size_t)b * N * 3;
  const float* __restrict__ xb = xyz + (size_t)b * N * 3;

  // Early: f0 + first row load — in flight through all of phase A.
  int f0 = 0;
  int3 row = make_int3(0, 0, 0);
  if (active) {
    f0 = centers[w];
    row = *reinterpret_cast<const int3*>(nb + 3 * (size_t)f0);
  }

  // ---- Phase A0: wave 0 = 16 carry chains; waves 1-15 = L2 prewarm -------
  if (wv == 0) {
    if (lane < WPB && (w0 + lane) < num_walks) {
      uint32_t ka, kb;
      tf2x32(0u, 42u, 0u, (uint32_t)(w0 + lane), ka, kb);  // k_0
      keys[lane][0] = make_uint2(ka, kb);
#pragma clang loop unroll(disable)
      for (int c = 1; c < CH; ++c) {
        tf2x32(ka, kb, 0u, 0u, ka, kb);
        keys[lane][c] = make_uint2(ka, kb);
      }
    }
  } else {
    // Stream this batch's neighbor table + xyz into L2 (sink via asm).
    const int nq = (N * 3) >> 2;   // int4 count (15000 for N=20000)
    const int j0 = tid - 64;       // 0..959
    const int4* __restrict__ pn = reinterpret_cast<const int4*>(nb);
    const int4* __restrict__ px = reinterpret_cast<const int4*>(xb);
    int acc = 0;
    for (int j = j0; j < nq; j += 960) {
      const int4 a = pn[j];
      const int4 c4 = px[j];
      acc ^= a.x ^ a.y ^ a.z ^ a.w ^ c4.x ^ c4.y ^ c4.z ^ c4.w;
    }
    asm volatile("" :: "v"(acc));  // keep the loads
  }
  __syncthreads();
  if (!active) return;

  // Issue first speculative triplet (row arrived long ago); flies during A1.
  int3 t0 = *reinterpret_cast<const int3*>(nb + 3 * (size_t)row.x);
  int3 t1 = *reinterpret_cast<const int3*>(nb + 3 * (size_t)row.y);
  int3 t2 = *reinterpret_cast<const int3*>(nb + 3 * (size_t)row.z);

  // ---- Phase A1: lane c = step-c randint tree (wave-local; no barrier) ---
  {
    const uint2 kc = keys[wv][lane];
    uint32_t k1a, k1b, hi, lo;
    tf2x32(kc.x, kc.y, 0u, 1u, k1a, k1b);  // k1 = split(k,4)[1]
    randbits(k1a, k1b, hi, lo);
    pre[wv][lane] = pick_code(hi, lo);
  }

  // ---- Phase B: wave-uniform decision loop -------------------------------
  // visited set: lane j holds the j-th visited node (slot 0 = f0).
  int hist  = (lane == 0) ? f0 : -1;
  int hist2 = -1;              // slots 64..127 (backtrack overflow; ~never)
  int seqr  = (lane == 0) ? f0 : -1;  // lane t = seq[t]

  uint32_t extka = 0, extkb = 0;
  int extc = -1;  // lazy chain extension beyond CH (only after backtracks)

  auto get_key = [&](int idx, uint32_t& ra, uint32_t& rb) {
    if (idx < CH) {
      const uint2 q = keys[wv][idx]; ra = q.x; rb = q.y;
    } else {
      if (extc < 0) { const uint2 q = keys[wv][CH - 1]; extka = q.x; extkb = q.y; extc = CH - 1; }
      while (extc < idx) { tf2x32(extka, extkb, 0u, 0u, extka, extkb); ++extc; }
      ra = extka; rb = extkb;
    }
  };

  uint32_t code_next = pre[wv][0];
  int i = 1, bs = 1, c = 0;

  while (i <= L) {
    const int idx = c; ++c;
    const bool deep = (idx >= CH);  // hist2 in use
    const uint32_t codeP = code_next;
    code_next = pre[wv][(c < CH) ? c : 0];  // prefetch next (off crit path)

    const int n0 = row.x, n1 = row.y, n2 = row.z;
    int v0 = __any(hist == n0), v1 = __any(hist == n1), v2 = __any(hist == n2);
    if (deep) {
      v0 |= __any(hist2 == n0); v1 |= __any(hist2 == n1); v2 |= __any(hist2 == n2);
    }
    const int u0 = 1 - v0, u1 = 1 - v1, u2 = 1 - v2;
    const int cnt = u0 + u1 + u2;

    int to_add;
    int sel = -1;        // >=0: common path, row select from triplet
    bool hit = false;
    int bsf = bs;
    if (cnt > 0) {
      uint32_t code;
      if (!deep) {
        code = codeP;
      } else {  // rare: live tree beyond cached steps
        uint32_t ia, ib, k1a, k1b, hi, lo;
        get_key(idx, ia, ib);
        tf2x32(ia, ib, 0u, 1u, k1a, k1b);
        randbits(k1a, k1b, hi, lo);
        code = pick_code(hi, lo);
      }
      const int r3 = (int)(code & 3u), r2 = (int)((code >> 2) & 1u);
      const int target = (cnt == 3 ? r3 : (cnt == 2 ? r2 : 0)) + 1;
      sel = (u0 == target) ? 0 : ((u0 + u1 == target) ? 1 : 2);
      to_add = (sel == 0) ? n0 : ((sel == 1) ? n1 : n2);
    } else {
      // ---- rare backtrack path (live hashing, bit-exact) ----
      uint32_t kia, kib;
      get_key(idx, kia, kib);
      uint32_t kka, kkb;
      tf2x32(kia, kib, 0u, 2u, kka, kkb);  // k2
      bool found = false;
      int ta = 0, bsc = bs;
      while (!found && i > bsc) {
        uint32_t ca, cb, kpa, kpb;
        tf2x32(kka, kkb, 0u, 0u, ca, cb);    // kk = split[0]
        tf2x32(kka, kkb, 0u, 1u, kpa, kpb);  // kp = split[1]
        const int back = __shfl(seqr, i - bsc - 1);
        const int3 br = *reinterpret_cast<const int3*>(nb + 3 * (size_t)back);
        int w0m = __any(hist == br.x), w1m = __any(hist == br.y), w2m = __any(hist == br.z);
        if (deep) {
          w0m |= __any(hist2 == br.x); w1m |= __any(hist2 == br.y); w2m |= __any(hist2 == br.z);
        }
        const int e0 = 1 - w0m, e1 = 1 - w1m, e2 = 1 - w2m;
        const int bc = e0 + e1 + e2;
        if (bc > 0) {
          uint32_t bhi, blo;
          randbits(kpa, kpb, bhi, blo);
          const uint32_t bcode = pick_code(bhi, blo);
          const int r3 = (int)(bcode & 3u), r2 = (int)((bcode >> 2) & 1u);
          const int t2v = (bc == 3 ? r3 : (bc == 2 ? r2 : 0)) + 1;
          ta = (e0 == t2v) ? br.x : ((e0 + e1 == t2v) ? br.y : br.z);
          found = true;
        } else {
          bsc += 2;
        }
        kka = ca; kkb = cb;
      }
      if (found) {
        to_add = ta; hit = true; bsf = bsc;
      } else {
        uint32_t k3a, k3b, rhi, rlo;
        tf2x32(kia, kib, 0u, 3u, k3a, k3b);  // k3
        randbits(k3a, k3b, rhi, rlo);
        to_add = (int)r_generic(rhi, rlo, (uint32_t)N);
      }
    }

    int i_new, up;
    if (hit) { i_new = i - bsf; bs = bsf; up = i - 1; }   // splat [i_new, i)
    else     { i_new = i;       bs = 1;   up = i; }
    seqr = (lane >= i_new && lane <= up) ? to_add : seqr;

    const int slot = idx + 1;
    if (slot < CH)            hist  = (lane == slot)      ? to_add : hist;
    else if (slot < 2 * CH)   hist2 = (lane == slot - CH) ? to_add : hist2;
    // slot >= 128: needs ~32 backtracks in one walk — P < 1e-100 here.

    i = i_new + 1;

    // Next row: common path = select from in-flight triplet; rare = reload.
    if (sel >= 0) {
      row.x = (sel == 0) ? t0.x : ((sel == 1) ? t1.x : t2.x);
      row.y = (sel == 0) ? t0.y : ((sel == 1) ? t1.y : t2.y);
      row.z = (sel == 0) ? t0.z : ((sel == 1) ? t1.z : t2.z);
    } else {
      row = *reinterpret_cast<const int3*>(nb + 3 * (size_t)to_add);
    }
    // Issue next speculative triplet.
    t0 = *reinterpret_cast<const int3*>(nb + 3 * (size_t)row.x);
    t1 = *reinterpret_cast<const int3*>(nb + 3 * (size_t)row.y);
    t2 = *reinterpret_cast<const int3*>(nb + 3 * (size_t)row.z);
  }

  // ---- Epilogue: lane t holds seq[t]; xyz is L2-warm ---------------------
  const float cx = xb[3 * (size_t)f0 + 0];
  const float cy = xb[3 * (size_t)f0 + 1];
  const float cz = xb[3 * (size_t)f0 + 2];
  if (lane < Lp1) {
    const int node = seqr;
    float3 v;
    v.x = xb[3 * (size_t)node + 0] - cx;
    v.y = xb[3 * (size_t)node + 1] - cy;
    v.z = xb[3 * (size_t)node + 2] - cz;
    *reinterpret_cast<float3*>(out + ((size_t)w * Lp1 + lane) * 3) = v;
  }
}

}  // namespace

extern "C" void kernel_launch(void* const* d_in, const int* in_sizes, int n_in,
                              void* d_out, int out_size, void* d_ws, size_t ws_size,
                              hipStream_t stream) {
  const float* xyz     = (const float*)d_in[0];
  const int*   nbrs    = (const int*)d_in[1];
  const int*   centers = (const int*)d_in[2];
  const int*   n_faces = (const int*)d_in[3];
  const int*   seq_len = (const int*)d_in[4];
  float* out = (float*)d_out;

  const int s0 = in_sizes[0];                  // B*N*3
  const int num_walks = in_sizes[2];           // B*G = 4096
  const int Lp1 = out_size / (3 * num_walks);  // 64

  const int blocks = (num_walks + WPB - 1) / WPB;  // 256
  walk_kernel<<<blocks, WPB * 64, 0, stream>>>(
      xyz, nbrs, centers, n_faces, seq_len, out, s0, num_walks, Lp1);
}